// Round 17
// baseline (89.849 us; speedup 1.0000x reference)
//
#include <hip/hip_runtime.h>

#define KCODES 512
#define DDIM   64
#define NROWS  131072

typedef short bf16x8 __attribute__((ext_vector_type(8)));
typedef float f32x4  __attribute__((ext_vector_type(4)));
typedef int   i32x4  __attribute__((ext_vector_type(4)));

union frag_cast { i32x4 i; bf16x8 h; };

__device__ __forceinline__ unsigned f32_to_bf16_rne(float x) {
    unsigned u = __float_as_uint(x);
    return (u + 0x7fffu + ((u >> 16) & 1u)) >> 16;   // RNE (finite/normal data)
}

// global -> LDS direct DMA, 16B per lane (lds dest = wave-uniform base + lane*16)
__device__ __forceinline__ void gload16(const void* g, void* l) {
    __builtin_amdgcn_global_load_lds(
        (const __attribute__((address_space(1))) void*)g,
        (__attribute__((address_space(3))) void*)l, 16, 0, 0);
}

// ---------------- K1: e_norm + per-block emax + split-bf16 B-frags ----------
__global__ __launch_bounds__(64) void k1_prep(const float* __restrict__ emb,
                                              float* __restrict__ en, float* __restrict__ emaxp,
                                              i32x4* __restrict__ efA, i32x4* __restrict__ efB) {
    const int kt = blockIdx.x, t = threadIdx.x;
    const int krow = t & 15, gq = t >> 4;
    const int k = kt * 16 + krow;

    float er[16];
    float pz = 0.f;
#pragma unroll
    for (int c = 0; c < 2; ++c)
#pragma unroll
        for (int j = 0; j < 8; ++j) {
            float x = emb[k * DDIM + c * 32 + gq * 8 + j];
            er[c * 8 + j] = x;
            pz = fmaf(x, x, pz);
        }

#pragma unroll
    for (int c = 0; c < 2; ++c) {
        unsigned hh[8], hl[8];
#pragma unroll
        for (int j = 0; j < 8; ++j) {
            float x = er[c * 8 + j];
            unsigned h = f32_to_bf16_rne(x);
            float hf = __uint_as_float(h << 16);
            hh[j] = h;
            hl[j] = f32_to_bf16_rne(x - hf);
        }
        i32x4 wh, wl;
#pragma unroll
        for (int i = 0; i < 4; ++i) {
            wh[i] = (int)(hh[2 * i] | (hh[2 * i + 1] << 16));
            wl[i] = (int)(hl[2 * i] | (hl[2 * i + 1] << 16));
        }
        int idx = (kt * 2 + c) * 64 + krow + 16 * gq;
        efA[idx] = wh;
        efB[idx] = wl;
    }

    pz += __shfl_xor(pz, 16);
    pz += __shfl_xor(pz, 32);
    if (t < 16) en[k] = pz;

    float m = pz;
#pragma unroll
    for (int sh = 1; sh <= 8; sh <<= 1) m = fmaxf(m, __shfl_xor(m, sh));
    if (t == 0) emaxp[kt] = m;   // norm^2 partial max; k3 reduces the 32
}

// ---------------- K3: 4 waves x 2 tiles; wave-private TRIPLE-buffered DMA frags -----
// No lgkmcnt(0)/sched_barrier in loop: write target != read buffer (3-buf rotation).
__global__ __launch_bounds__(256, 4) void k3_fused(
    const float* __restrict__ z, const float* __restrict__ emb,
    const i32x4* __restrict__ efA_, const i32x4* __restrict__ efB_,
    const float* __restrict__ en_g, const float* __restrict__ emaxp,
    int* __restrict__ out) {

    __shared__ i32x4 sfrag[4][3][4][64];   // 48 KB: [wave][buf][slot][lane]
    __shared__ float en_l[KCODES];         // 2 KB
    __shared__ float zn_l[128];
    __shared__ int   flag_rows[128];
    __shared__ int   nflag;
    // ~52 KB -> 3 blocks/CU, 12 waves/CU

    const int t = threadIdx.x, blk = blockIdx.x;
    const int n0 = blk * 128;
    const int b = n0 >> 12, hw0 = n0 & 4095;   // 32 blocks per b -> b uniform
    const int w = t >> 6, lane = t & 63;
    const int klane = lane & 15, g = lane >> 4;

    if (t == 0) nflag = 0;

    en_l[t] = en_g[t];
    en_l[t + 256] = en_g[t + 256];

    float em2 = 0.f;
#pragma unroll
    for (int i = 0; i < 32; ++i) em2 = fmaxf(em2, emaxp[i]);
    const float emax = sqrtf(em2) * 1.0001f;

    // ---- z gather + split-bf16 A-frags + zn
    const float* zbase = z + (size_t)b * (DDIM * 4096) + hw0;
    bf16x8 zh[2][2], zl[2][2];
#pragma unroll
    for (int tl = 0; tl < 2; ++tl) {
        const int row = w * 32 + tl * 16 + klane;
        float zv[16];
#pragma unroll
        for (int c = 0; c < 2; ++c)
#pragma unroll
            for (int j = 0; j < 8; ++j)
                zv[c * 8 + j] = zbase[(size_t)(c * 32 + g * 8 + j) * 4096 + row];
        float pz = 0.f;
#pragma unroll
        for (int c = 0; c < 2; ++c) {
            unsigned hh[8], hl[8];
#pragma unroll
            for (int j = 0; j < 8; ++j) {
                float x = zv[c * 8 + j];
                pz = fmaf(x, x, pz);
                unsigned h = f32_to_bf16_rne(x);
                float hf = __uint_as_float(h << 16);
                hh[j] = h;
                hl[j] = f32_to_bf16_rne(x - hf);
            }
            frag_cast uh, ul;
#pragma unroll
            for (int i = 0; i < 4; ++i) {
                uh.i[i] = (int)(hh[2 * i] | (hh[2 * i + 1] << 16));
                ul.i[i] = (int)(hl[2 * i] | (hl[2 * i + 1] << 16));
            }
            zh[tl][c] = uh.h;
            zl[tl][c] = ul.h;
        }
        pz += __shfl_xor(pz, 16);
        pz += __shfl_xor(pz, 32);
        if (g == 0) zn_l[w * 32 + tl * 16 + klane] = pz;
    }
    __syncthreads();   // en_l/zn_l visible; prologue vmem drained

    float m1[2][4], m2[2][4];
    int i1[2][4];
#pragma unroll
    for (int tl = 0; tl < 2; ++tl)
#pragma unroll
        for (int r = 0; r < 4; ++r) { m1[tl][r] = 3.4e38f; m2[tl][r] = 3.4e38f; i1[tl][r] = 0; }

    f32x4 zero = {0.f, 0.f, 0.f, 0.f};

    // DMA one kt into this wave's buf (4 x 1KB; vmcnt += 4) — no VGPRs consumed
    auto issue = [&](int kt, int buf) {
        const i32x4* gA = efA_ + kt * 128 + lane;
        const i32x4* gB = efB_ + kt * 128 + lane;
        gload16(gA,      &sfrag[w][buf][0][0]);
        gload16(gA + 64, &sfrag[w][buf][1][0]);
        gload16(gB,      &sfrag[w][buf][2][0]);
        gload16(gB + 64, &sfrag[w][buf][3][0]);
    };

    issue(0, 0);
    issue(1, 1);

    // ---- main: barrier-free, counted vmcnt, depth-2 pipeline into 3 rotating bufs.
    // Read buf (kt%3) != write buf ((kt+2)%3): no same-buffer hazard -> compiler
    // emits fine-grained lgkmcnt, ds_reads overlap MFMAs across iterations.
    int rbuf = 0;
#pragma unroll 1
    for (int kt = 0; kt < 32; ++kt) {
        if (kt < 31) { asm volatile("s_waitcnt vmcnt(4)" ::: "memory"); }
        else         { asm volatile("s_waitcnt vmcnt(0)" ::: "memory"); }

        frag_cast e0h, e1h, e0l, e1l;
        e0h.i = sfrag[w][rbuf][0][lane];
        e1h.i = sfrag[w][rbuf][1][lane];
        e0l.i = sfrag[w][rbuf][2][lane];
        e1l.i = sfrag[w][rbuf][3][lane];
        if (kt < 30) {
            int wbuf = rbuf + 2; if (wbuf >= 3) wbuf -= 3;   // (kt+2)%3
            issue(kt + 2, wbuf);
        }

        const int k = kt * 16 + klane;
        const float enk = en_l[k];
#pragma unroll
        for (int tl = 0; tl < 2; ++tl) {
            f32x4 acc = __builtin_amdgcn_mfma_f32_16x16x32_bf16(zh[tl][0], e0h.h, zero, 0, 0, 0);
            acc = __builtin_amdgcn_mfma_f32_16x16x32_bf16(zh[tl][1], e1h.h, acc, 0, 0, 0);
            acc = __builtin_amdgcn_mfma_f32_16x16x32_bf16(zh[tl][0], e0l.h, acc, 0, 0, 0);
            acc = __builtin_amdgcn_mfma_f32_16x16x32_bf16(zh[tl][1], e1l.h, acc, 0, 0, 0);
            acc = __builtin_amdgcn_mfma_f32_16x16x32_bf16(zl[tl][0], e0h.h, acc, 0, 0, 0);
            acc = __builtin_amdgcn_mfma_f32_16x16x32_bf16(zl[tl][1], e1h.h, acc, 0, 0, 0);
#pragma unroll
            for (int r = 0; r < 4; ++r) {
                float d = fmaf(-2.f, acc[r], enk);   // shifted: zn cancels (validated r13-16)
                float o1 = m1[tl][r];
                i1[tl][r] = (d < o1) ? k : i1[tl][r];
                m2[tl][r] = fminf(m2[tl][r], fmaxf(o1, d));
                m1[tl][r] = fminf(o1, d);
            }
        }
        rbuf = (rbuf + 1 == 3) ? 0 : rbuf + 1;
    }

    // reduce across the 16 code-lanes: xor 1,2,4,8
#pragma unroll
    for (int sh = 1; sh <= 8; sh <<= 1) {
#pragma unroll
        for (int tl = 0; tl < 2; ++tl)
#pragma unroll
            for (int r = 0; r < 4; ++r) {
                float om1 = __shfl_xor(m1[tl][r], sh);
                int oi1 = __shfl_xor(i1[tl][r], sh);
                float om2 = __shfl_xor(m2[tl][r], sh);
                float hi = fmaxf(m1[tl][r], om1);
                m2[tl][r] = fminf(fminf(m2[tl][r], om2), hi);
                i1[tl][r] = (om1 < m1[tl][r]) ? oi1 : i1[tl][r];
                m1[tl][r] = fminf(m1[tl][r], om1);
            }
    }

    if (klane == 0) {
#pragma unroll
        for (int tl = 0; tl < 2; ++tl) {
            int rowbase = n0 + w * 32 + tl * 16 + g * 4;
            i32x4 idx4;
#pragma unroll
            for (int r = 0; r < 4; ++r) idx4[r] = i1[tl][r];
            *(i32x4*)(out + rowbase) = idx4;
#pragma unroll
            for (int r = 0; r < 4; ++r) {
                float zz = zn_l[w * 32 + tl * 16 + g * 4 + r];
                // |split-mfma dist - fp32 dist| bound (~3x margin), validated r5-r16
                float W = fmaf(sqrtf(zz) * emax, 1.0e-4f, zz * 1.0e-6f);
                if (m2[tl][r] - m1[tl][r] <= W) {
                    int p = atomicAdd(&nflag, 1);
                    flag_rows[p] = w * 32 + tl * 16 + g * 4 + r;   // local row
                }
            }
        }
    }
    __syncthreads();

    // ---- in-block exact fp32 refine (k4 semantics); zrow aliases the frag buffer
    float (*zrow_s)[64] = (float(*)[64])&sfrag[0][0][0][0];
    const int nf = nflag;
    for (int i = w; i < nf; i += 4) {
        const int lrow = flag_rows[i];
        zrow_s[w][lane] = zbase[(size_t)lane * 4096 + lrow];
        const float znr = zn_l[lrow];
        float best = 3.4e38f;
        int bi = 0;
#pragma unroll 1
        for (int kk = 0; kk < 8; ++kk) {
            int k = lane * 8 + kk;
            const float* e0 = emb + k * DDIM;
            float acc = 0.f;
#pragma unroll
            for (int d = 0; d < DDIM; ++d) acc = fmaf(e0[d], zrow_s[w][d], acc);
            float dist = fmaf(-2.f, acc, znr + en_l[k]);
            if (dist < best) { best = dist; bi = k; }   // ascending k: first-occurrence
        }
        unsigned long long key =
            ((unsigned long long)__float_as_uint(best) << 32) | (unsigned)bi;
#pragma unroll
        for (int sh = 32; sh; sh >>= 1) {
            unsigned long long o = __shfl_xor(key, sh);
            key = (o < key) ? o : key;
        }
        if (lane == 0) out[n0 + lrow] = (int)(key & 0xFFFFFFFFull);
    }
}

// ---------------- fallback (round-1, known-good) ----------------
__global__ void fb_enorm(const float* __restrict__ emb, float* __restrict__ en) {
    int k = blockIdx.x * blockDim.x + threadIdx.x;
    if (k < KCODES) {
        float s = 0.f;
#pragma unroll
        for (int d = 0; d < DDIM; ++d) { float e = emb[k * DDIM + d]; s = fmaf(e, e, s); }
        en[k] = s;
    }
}
__global__ __launch_bounds__(256) void fb_argmin(const float* __restrict__ z,
                                                 const float* __restrict__ emb,
                                                 const float* __restrict__ en,
                                                 int* __restrict__ out, int nrows) {
    int n = blockIdx.x * blockDim.x + threadIdx.x;
    if (n >= nrows) return;
    int b = n >> 12, hw = n & 4095;
    const float* zp = z + (size_t)b * (DDIM * 4096) + hw;
    float zr[DDIM];
#pragma unroll
    for (int d = 0; d < DDIM; ++d) zr[d] = zp[(size_t)d * 4096];
    float zn = 0.f;
#pragma unroll
    for (int d = 0; d < DDIM; ++d) zn = fmaf(zr[d], zr[d], zn);
    float best = 3.4e38f; int bi = 0;
    for (int k0 = 0; k0 < KCODES; k0 += 8) {
        float acc[8];
#pragma unroll
        for (int kk = 0; kk < 8; ++kk) acc[kk] = 0.f;
        const float* e0 = emb + k0 * DDIM;
#pragma unroll
        for (int d = 0; d < DDIM; ++d) {
            float zd = zr[d];
#pragma unroll
            for (int kk = 0; kk < 8; ++kk) acc[kk] = fmaf(e0[kk * DDIM + d], zd, acc[kk]);
        }
#pragma unroll
        for (int kk = 0; kk < 8; ++kk) {
            float dist = fmaf(-2.f, acc[kk], zn + en[k0 + kk]);
            if (dist < best) { best = dist; bi = k0 + kk; }
        }
    }
    out[n] = bi;
}

extern "C" void kernel_launch(void* const* d_in, const int* in_sizes, int n_in,
                              void* d_out, int out_size, void* d_ws, size_t ws_size,
                              hipStream_t stream) {
    const float* z   = (const float*)d_in[0];   // [32,64,64,64] fp32
    const float* emb = (const float*)d_in[1];   // [512,64] fp32
    int* out = (int*)d_out;                     // 131072 int32

    const size_t SZ_EF   = 32 * 2 * 64 * 16;    // 64 KB each
    const size_t SZ_EN   = KCODES * 4;
    const size_t SZ_EMAX = 128;
    const size_t NEED = 2 * SZ_EF + SZ_EN + SZ_EMAX;   // ~130 KB

    if (ws_size < NEED) {   // safety net: round-1 path
        float* en = (float*)d_ws;
        fb_enorm<<<2, 256, 0, stream>>>(emb, en);
        fb_argmin<<<NROWS / 256, 256, 0, stream>>>(z, emb, en, out, NROWS);
        return;
    }

    char* p = (char*)d_ws;
    i32x4* efA = (i32x4*)p;   p += SZ_EF;
    i32x4* efB = (i32x4*)p;   p += SZ_EF;
    float* en  = (float*)p;   p += SZ_EN;
    float* emaxp = (float*)p;

    k1_prep<<<32, 64, 0, stream>>>(emb, en, emaxp, efA, efB);
    k3_fused<<<NROWS / 128, 256, 0, stream>>>(z, emb, efA, efB, en, emaxp, out);
}

// Round 18
// 82.164 us; speedup vs baseline: 1.0935x; 1.0935x over previous
//
#include <hip/hip_runtime.h>

#define KCODES 512
#define DDIM   64
#define NROWS  131072

typedef short bf16x8 __attribute__((ext_vector_type(8)));
typedef float f32x4  __attribute__((ext_vector_type(4)));
typedef int   i32x4  __attribute__((ext_vector_type(4)));

union frag_cast { i32x4 i; bf16x8 h; };

__device__ __forceinline__ unsigned f32_to_bf16_rne(float x) {
    unsigned u = __float_as_uint(x);
    return (u + 0x7fffu + ((u >> 16) & 1u)) >> 16;   // RNE (finite/normal data)
}

// global -> LDS direct DMA, 16B per lane (lds dest = wave-uniform base + lane*16)
__device__ __forceinline__ void gload16(const void* g, void* l) {
    __builtin_amdgcn_global_load_lds(
        (const __attribute__((address_space(1))) void*)g,
        (__attribute__((address_space(3))) void*)l, 16, 0, 0);
}

// ---------------- K1: e_norm + per-block emax + split-bf16 B-frags ----------
__global__ __launch_bounds__(64) void k1_prep(const float* __restrict__ emb,
                                              float* __restrict__ en, float* __restrict__ emaxp,
                                              i32x4* __restrict__ efA, i32x4* __restrict__ efB) {
    const int kt = blockIdx.x, t = threadIdx.x;
    const int krow = t & 15, gq = t >> 4;
    const int k = kt * 16 + krow;

    float er[16];
    float pz = 0.f;
#pragma unroll
    for (int c = 0; c < 2; ++c)
#pragma unroll
        for (int j = 0; j < 8; ++j) {
            float x = emb[k * DDIM + c * 32 + gq * 8 + j];
            er[c * 8 + j] = x;
            pz = fmaf(x, x, pz);
        }

#pragma unroll
    for (int c = 0; c < 2; ++c) {
        unsigned hh[8], hl[8];
#pragma unroll
        for (int j = 0; j < 8; ++j) {
            float x = er[c * 8 + j];
            unsigned h = f32_to_bf16_rne(x);
            float hf = __uint_as_float(h << 16);
            hh[j] = h;
            hl[j] = f32_to_bf16_rne(x - hf);
        }
        i32x4 wh, wl;
#pragma unroll
        for (int i = 0; i < 4; ++i) {
            wh[i] = (int)(hh[2 * i] | (hh[2 * i + 1] << 16));
            wl[i] = (int)(hl[2 * i] | (hl[2 * i + 1] << 16));
        }
        int idx = (kt * 2 + c) * 64 + krow + 16 * gq;
        efA[idx] = wh;
        efB[idx] = wl;
    }

    pz += __shfl_xor(pz, 16);
    pz += __shfl_xor(pz, 32);
    if (t < 16) en[k] = pz;

    float m = pz;
#pragma unroll
    for (int sh = 1; sh <= 8; sh <<= 1) m = fmaxf(m, __shfl_xor(m, sh));
    if (t == 0) emaxp[kt] = m;   // norm^2 partial max; k3 reduces the 32
}

// ---------------- K3: 4 waves x 2 tiles; BLOCK-SHARED triple-buffered staging -------
// Each wave DMAs 1 KB/kt (its slot) -> L2 codebook traffic 128 MB (4x less).
// 3-buf rotation: write-buf != read-buf -> no lgkmcnt(0) drain needed.
// One raw s_barrier + own-vmcnt(1) per kt (m201 pattern). LDS ~15.3 KB.
__global__ __launch_bounds__(256, 4) void k3_fused(
    const float* __restrict__ z, const float* __restrict__ emb,
    const i32x4* __restrict__ efA_, const i32x4* __restrict__ efB_,
    const float* __restrict__ en_g, const float* __restrict__ emaxp,
    int* __restrict__ out) {

    __shared__ i32x4 sfrag[3][4][64];   // 12 KB: [buf][slot][lane], one kt per buf
    __shared__ float en_l[KCODES];      // 2 KB
    __shared__ float zn_l[128];
    __shared__ int   flag_rows[128];
    __shared__ int   nflag;

    const int t = threadIdx.x, blk = blockIdx.x;
    const int n0 = blk * 128;
    const int b = n0 >> 12, hw0 = n0 & 4095;   // 32 blocks per b -> b uniform
    const int w = t >> 6, lane = t & 63;
    const int klane = lane & 15, g = lane >> 4;

    if (t == 0) nflag = 0;

    // wave w stages slot w of kt (1 KB): slots 0,1 = hi halves, 2,3 = lo halves
    auto issue = [&](int kt, int buf) {
        const i32x4* src = (w < 2 ? efA_ : efB_) + (size_t)kt * 128 + (w & 1) * 64 + lane;
        gload16(src, &sfrag[buf][w][0]);
    };

    issue(0, 0);
    issue(1, 1);

    en_l[t] = en_g[t];
    en_l[t + 256] = en_g[t + 256];

    float em2 = 0.f;
#pragma unroll
    for (int i = 0; i < 32; ++i) em2 = fmaxf(em2, emaxp[i]);
    const float emax = sqrtf(em2) * 1.0001f;

    // ---- z gather + split-bf16 A-frags + zn
    const float* zbase = z + (size_t)b * (DDIM * 4096) + hw0;
    bf16x8 zh[2][2], zl[2][2];
#pragma unroll
    for (int tl = 0; tl < 2; ++tl) {
        const int row = w * 32 + tl * 16 + klane;
        float zv[16];
#pragma unroll
        for (int c = 0; c < 2; ++c)
#pragma unroll
            for (int j = 0; j < 8; ++j)
                zv[c * 8 + j] = zbase[(size_t)(c * 32 + g * 8 + j) * 4096 + row];
        float pz = 0.f;
#pragma unroll
        for (int c = 0; c < 2; ++c) {
            unsigned hh[8], hl[8];
#pragma unroll
            for (int j = 0; j < 8; ++j) {
                float x = zv[c * 8 + j];
                pz = fmaf(x, x, pz);
                unsigned h = f32_to_bf16_rne(x);
                float hf = __uint_as_float(h << 16);
                hh[j] = h;
                hl[j] = f32_to_bf16_rne(x - hf);
            }
            frag_cast uh, ul;
#pragma unroll
            for (int i = 0; i < 4; ++i) {
                uh.i[i] = (int)(hh[2 * i] | (hh[2 * i + 1] << 16));
                ul.i[i] = (int)(hl[2 * i] | (hl[2 * i + 1] << 16));
            }
            zh[tl][c] = uh.h;
            zl[tl][c] = ul.h;
        }
        pz += __shfl_xor(pz, 16);
        pz += __shfl_xor(pz, 32);
        if (g == 0) zn_l[w * 32 + tl * 16 + klane] = pz;
    }
    __syncthreads();   // en_l/zn_l visible; prologue (incl. chunk0/1 DMA) drained

    float m1[2][4], m2[2][4];
    int i1[2][4];
#pragma unroll
    for (int tl = 0; tl < 2; ++tl)
#pragma unroll
        for (int r = 0; r < 4; ++r) { m1[tl][r] = 3.4e38f; m2[tl][r] = 3.4e38f; i1[tl][r] = 0; }

    f32x4 zero = {0.f, 0.f, 0.f, 0.f};

    // ---- main: 1 raw barrier + own-vmcnt per kt; 3-buf rotation, no lgkm drain.
    // Safety: a wave's ds_reads of buf X (kt-1) retire before its MFMAs (in-order),
    // which precede barrier kt; issue(kt+2)->X happens after barrier kt.
    int rbuf = 0;
#pragma unroll 1
    for (int kt = 0; kt < 32; ++kt) {
        if (kt < 31) { asm volatile("s_waitcnt vmcnt(1)" ::: "memory"); }
        else         { asm volatile("s_waitcnt vmcnt(0)" ::: "memory"); }
        __builtin_amdgcn_s_barrier();   // all 4 slots of kt visible to all waves
        if (kt + 2 < 32) {
            int wbuf = rbuf + 2; if (wbuf >= 3) wbuf -= 3;
            issue(kt + 2, wbuf);
        }

        frag_cast e0h, e1h, e0l, e1l;
        e0h.i = sfrag[rbuf][0][lane];
        e1h.i = sfrag[rbuf][1][lane];
        e0l.i = sfrag[rbuf][2][lane];
        e1l.i = sfrag[rbuf][3][lane];

        const int k = kt * 16 + klane;
        const float enk = en_l[k];
#pragma unroll
        for (int tl = 0; tl < 2; ++tl) {
            f32x4 acc = __builtin_amdgcn_mfma_f32_16x16x32_bf16(zh[tl][0], e0h.h, zero, 0, 0, 0);
            acc = __builtin_amdgcn_mfma_f32_16x16x32_bf16(zh[tl][1], e1h.h, acc, 0, 0, 0);
            acc = __builtin_amdgcn_mfma_f32_16x16x32_bf16(zh[tl][0], e0l.h, acc, 0, 0, 0);
            acc = __builtin_amdgcn_mfma_f32_16x16x32_bf16(zh[tl][1], e1l.h, acc, 0, 0, 0);
            acc = __builtin_amdgcn_mfma_f32_16x16x32_bf16(zl[tl][0], e0h.h, acc, 0, 0, 0);
            acc = __builtin_amdgcn_mfma_f32_16x16x32_bf16(zl[tl][1], e1h.h, acc, 0, 0, 0);
#pragma unroll
            for (int r = 0; r < 4; ++r) {
                float d = fmaf(-2.f, acc[r], enk);   // shifted: zn cancels (validated r13-17)
                float o1 = m1[tl][r];
                i1[tl][r] = (d < o1) ? k : i1[tl][r];
                m2[tl][r] = fminf(m2[tl][r], fmaxf(o1, d));
                m1[tl][r] = fminf(o1, d);
            }
        }
        rbuf = (rbuf + 1 == 3) ? 0 : rbuf + 1;
    }

    // reduce across the 16 code-lanes: xor 1,2,4,8
#pragma unroll
    for (int sh = 1; sh <= 8; sh <<= 1) {
#pragma unroll
        for (int tl = 0; tl < 2; ++tl)
#pragma unroll
            for (int r = 0; r < 4; ++r) {
                float om1 = __shfl_xor(m1[tl][r], sh);
                int oi1 = __shfl_xor(i1[tl][r], sh);
                float om2 = __shfl_xor(m2[tl][r], sh);
                float hi = fmaxf(m1[tl][r], om1);
                m2[tl][r] = fminf(fminf(m2[tl][r], om2), hi);
                i1[tl][r] = (om1 < m1[tl][r]) ? oi1 : i1[tl][r];
                m1[tl][r] = fminf(m1[tl][r], om1);
            }
    }

    if (klane == 0) {
#pragma unroll
        for (int tl = 0; tl < 2; ++tl) {
            int rowbase = n0 + w * 32 + tl * 16 + g * 4;
            i32x4 idx4;
#pragma unroll
            for (int r = 0; r < 4; ++r) idx4[r] = i1[tl][r];
            *(i32x4*)(out + rowbase) = idx4;
#pragma unroll
            for (int r = 0; r < 4; ++r) {
                float zz = zn_l[w * 32 + tl * 16 + g * 4 + r];
                // |split-mfma dist - fp32 dist| bound (~3x margin), validated r5-r17
                float W = fmaf(sqrtf(zz) * emax, 1.0e-4f, zz * 1.0e-6f);
                if (m2[tl][r] - m1[tl][r] <= W) {
                    int p = atomicAdd(&nflag, 1);
                    flag_rows[p] = w * 32 + tl * 16 + g * 4 + r;   // local row
                }
            }
        }
    }
    __syncthreads();

    // ---- in-block exact fp32 refine (k4 semantics); zrow aliases the frag buffer
    float (*zrow_s)[64] = (float(*)[64])&sfrag[0][0][0];
    const int nf = nflag;
    for (int i = w; i < nf; i += 4) {
        const int lrow = flag_rows[i];
        zrow_s[w][lane] = zbase[(size_t)lane * 4096 + lrow];
        const float znr = zn_l[lrow];
        float best = 3.4e38f;
        int bi = 0;
#pragma unroll 1
        for (int kk = 0; kk < 8; ++kk) {
            int k = lane * 8 + kk;
            const float* e0 = emb + k * DDIM;
            float acc = 0.f;
#pragma unroll
            for (int d = 0; d < DDIM; ++d) acc = fmaf(e0[d], zrow_s[w][d], acc);
            float dist = fmaf(-2.f, acc, znr + en_l[k]);
            if (dist < best) { best = dist; bi = k; }   // ascending k: first-occurrence
        }
        unsigned long long key =
            ((unsigned long long)__float_as_uint(best) << 32) | (unsigned)bi;
#pragma unroll
        for (int sh = 32; sh; sh >>= 1) {
            unsigned long long o = __shfl_xor(key, sh);
            key = (o < key) ? o : key;
        }
        if (lane == 0) out[n0 + lrow] = (int)(key & 0xFFFFFFFFull);
    }
}

// ---------------- fallback (round-1, known-good) ----------------
__global__ void fb_enorm(const float* __restrict__ emb, float* __restrict__ en) {
    int k = blockIdx.x * blockDim.x + threadIdx.x;
    if (k < KCODES) {
        float s = 0.f;
#pragma unroll
        for (int d = 0; d < DDIM; ++d) { float e = emb[k * DDIM + d]; s = fmaf(e, e, s); }
        en[k] = s;
    }
}
__global__ __launch_bounds__(256) void fb_argmin(const float* __restrict__ z,
                                                 const float* __restrict__ emb,
                                                 const float* __restrict__ en,
                                                 int* __restrict__ out, int nrows) {
    int n = blockIdx.x * blockDim.x + threadIdx.x;
    if (n >= nrows) return;
    int b = n >> 12, hw = n & 4095;
    const float* zp = z + (size_t)b * (DDIM * 4096) + hw;
    float zr[DDIM];
#pragma unroll
    for (int d = 0; d < DDIM; ++d) zr[d] = zp[(size_t)d * 4096];
    float zn = 0.f;
#pragma unroll
    for (int d = 0; d < DDIM; ++d) zn = fmaf(zr[d], zr[d], zn);
    float best = 3.4e38f; int bi = 0;
    for (int k0 = 0; k0 < KCODES; k0 += 8) {
        float acc[8];
#pragma unroll
        for (int kk = 0; kk < 8; ++kk) acc[kk] = 0.f;
        const float* e0 = emb + k0 * DDIM;
#pragma unroll
        for (int d = 0; d < DDIM; ++d) {
            float zd = zr[d];
#pragma unroll
            for (int kk = 0; kk < 8; ++kk) acc[kk] = fmaf(e0[kk * DDIM + d], zd, acc[kk]);
        }
#pragma unroll
        for (int kk = 0; kk < 8; ++kk) {
            float dist = fmaf(-2.f, acc[kk], zn + en[k0 + kk]);
            if (dist < best) { best = dist; bi = k0 + kk; }
        }
    }
    out[n] = bi;
}

extern "C" void kernel_launch(void* const* d_in, const int* in_sizes, int n_in,
                              void* d_out, int out_size, void* d_ws, size_t ws_size,
                              hipStream_t stream) {
    const float* z   = (const float*)d_in[0];   // [32,64,64,64] fp32
    const float* emb = (const float*)d_in[1];   // [512,64] fp32
    int* out = (int*)d_out;                     // 131072 int32

    const size_t SZ_EF   = 32 * 2 * 64 * 16;    // 64 KB each
    const size_t SZ_EN   = KCODES * 4;
    const size_t SZ_EMAX = 128;
    const size_t NEED = 2 * SZ_EF + SZ_EN + SZ_EMAX;   // ~130 KB

    if (ws_size < NEED) {   // safety net: round-1 path
        float* en = (float*)d_ws;
        fb_enorm<<<2, 256, 0, stream>>>(emb, en);
        fb_argmin<<<NROWS / 256, 256, 0, stream>>>(z, emb, en, out, NROWS);
        return;
    }

    char* p = (char*)d_ws;
    i32x4* efA = (i32x4*)p;   p += SZ_EF;
    i32x4* efB = (i32x4*)p;   p += SZ_EF;
    float* en  = (float*)p;   p += SZ_EN;
    float* emaxp = (float*)p;

    k1_prep<<<32, 64, 0, stream>>>(emb, en, emaxp, efA, efB);
    k3_fused<<<NROWS / 128, 256, 0, stream>>>(z, emb, efA, efB, en, emaxp, out);
}

// Round 19
// 79.419 us; speedup vs baseline: 1.1313x; 1.0346x over previous
//
#include <hip/hip_runtime.h>

#define KCODES 512
#define DDIM   64
#define NROWS  131072

typedef short bf16x8 __attribute__((ext_vector_type(8)));
typedef float f32x4  __attribute__((ext_vector_type(4)));
typedef int   i32x4  __attribute__((ext_vector_type(4)));

union frag_cast { i32x4 i; bf16x8 h; };

__device__ __forceinline__ unsigned f32_to_bf16_rne(float x) {
    unsigned u = __float_as_uint(x);
    return (u + 0x7fffu + ((u >> 16) & 1u)) >> 16;   // RNE (finite/normal data)
}

// global -> LDS direct DMA, 16B per lane (lds dest = wave-uniform base + lane*16)
__device__ __forceinline__ void gload16(const void* g, void* l) {
    __builtin_amdgcn_global_load_lds(
        (const __attribute__((address_space(1))) void*)g,
        (__attribute__((address_space(3))) void*)l, 16, 0, 0);
}

// ---------------- K1: e_norm + per-block emax + split-bf16 B-frags ----------
__global__ __launch_bounds__(64) void k1_prep(const float* __restrict__ emb,
                                              float* __restrict__ en, float* __restrict__ emaxp,
                                              i32x4* __restrict__ efA, i32x4* __restrict__ efB) {
    const int kt = blockIdx.x, t = threadIdx.x;
    const int krow = t & 15, gq = t >> 4;
    const int k = kt * 16 + krow;

    float er[16];
    float pz = 0.f;
#pragma unroll
    for (int c = 0; c < 2; ++c)
#pragma unroll
        for (int j = 0; j < 8; ++j) {
            float x = emb[k * DDIM + c * 32 + gq * 8 + j];
            er[c * 8 + j] = x;
            pz = fmaf(x, x, pz);
        }

#pragma unroll
    for (int c = 0; c < 2; ++c) {
        unsigned hh[8], hl[8];
#pragma unroll
        for (int j = 0; j < 8; ++j) {
            float x = er[c * 8 + j];
            unsigned h = f32_to_bf16_rne(x);
            float hf = __uint_as_float(h << 16);
            hh[j] = h;
            hl[j] = f32_to_bf16_rne(x - hf);
        }
        i32x4 wh, wl;
#pragma unroll
        for (int i = 0; i < 4; ++i) {
            wh[i] = (int)(hh[2 * i] | (hh[2 * i + 1] << 16));
            wl[i] = (int)(hl[2 * i] | (hl[2 * i + 1] << 16));
        }
        int idx = (kt * 2 + c) * 64 + krow + 16 * gq;
        efA[idx] = wh;
        efB[idx] = wl;
    }

    pz += __shfl_xor(pz, 16);
    pz += __shfl_xor(pz, 32);
    if (t < 16) en[k] = pz;

    float m = pz;
#pragma unroll
    for (int sh = 1; sh <= 8; sh <<= 1) m = fmaxf(m, __shfl_xor(m, sh));
    if (t == 0) emaxp[kt] = m;   // norm^2 partial max; k3 reduces the 32
}

// ---------------- K3: r16 base (wave-private dbuf, counted vmcnt, barrier-free) -----
// ONLY change vs r16: 3 independent 2-MFMA chains per kt (ILP 3x) + end-combine.
__global__ __launch_bounds__(256, 4) void k3_fused(
    const float* __restrict__ z, const float* __restrict__ emb,
    const i32x4* __restrict__ efA_, const i32x4* __restrict__ efB_,
    const float* __restrict__ en_g, const float* __restrict__ emaxp,
    int* __restrict__ out) {

    __shared__ i32x4 sfrag[4][2][4][64];   // 32 KB: [wave][buf][slot][lane]
    __shared__ float en_l[KCODES];         // 2 KB
    __shared__ float zn_l[128];
    __shared__ int   flag_rows[128];
    __shared__ int   nflag;

    const int t = threadIdx.x, blk = blockIdx.x;
    const int n0 = blk * 128;
    const int b = n0 >> 12, hw0 = n0 & 4095;   // 32 blocks per b -> b uniform
    const int w = t >> 6, lane = t & 63;
    const int klane = lane & 15, g = lane >> 4;

    if (t == 0) nflag = 0;

    en_l[t] = en_g[t];
    en_l[t + 256] = en_g[t + 256];

    float em2 = 0.f;
#pragma unroll
    for (int i = 0; i < 32; ++i) em2 = fmaxf(em2, emaxp[i]);
    const float emax = sqrtf(em2) * 1.0001f;

    // ---- z gather + split-bf16 A-frags + zn
    const float* zbase = z + (size_t)b * (DDIM * 4096) + hw0;
    bf16x8 zh[2][2], zl[2][2];
#pragma unroll
    for (int tl = 0; tl < 2; ++tl) {
        const int row = w * 32 + tl * 16 + klane;
        float zv[16];
#pragma unroll
        for (int c = 0; c < 2; ++c)
#pragma unroll
            for (int j = 0; j < 8; ++j)
                zv[c * 8 + j] = zbase[(size_t)(c * 32 + g * 8 + j) * 4096 + row];
        float pz = 0.f;
#pragma unroll
        for (int c = 0; c < 2; ++c) {
            unsigned hh[8], hl[8];
#pragma unroll
            for (int j = 0; j < 8; ++j) {
                float x = zv[c * 8 + j];
                pz = fmaf(x, x, pz);
                unsigned h = f32_to_bf16_rne(x);
                float hf = __uint_as_float(h << 16);
                hh[j] = h;
                hl[j] = f32_to_bf16_rne(x - hf);
            }
            frag_cast uh, ul;
#pragma unroll
            for (int i = 0; i < 4; ++i) {
                uh.i[i] = (int)(hh[2 * i] | (hh[2 * i + 1] << 16));
                ul.i[i] = (int)(hl[2 * i] | (hl[2 * i + 1] << 16));
            }
            zh[tl][c] = uh.h;
            zl[tl][c] = ul.h;
        }
        pz += __shfl_xor(pz, 16);
        pz += __shfl_xor(pz, 32);
        if (g == 0) zn_l[w * 32 + tl * 16 + klane] = pz;
    }
    __syncthreads();   // en_l/zn_l visible; prologue vmem drained

    float m1[2][4], m2[2][4];
    int i1[2][4];
#pragma unroll
    for (int tl = 0; tl < 2; ++tl)
#pragma unroll
        for (int r = 0; r < 4; ++r) { m1[tl][r] = 3.4e38f; m2[tl][r] = 3.4e38f; i1[tl][r] = 0; }

    f32x4 zero = {0.f, 0.f, 0.f, 0.f};

    // DMA one kt into this wave's buf (4 x 1KB; vmcnt += 4) — no VGPRs consumed
    auto issue = [&](int kt, int buf) {
        const i32x4* gA = efA_ + kt * 128 + lane;
        const i32x4* gB = efB_ + kt * 128 + lane;
        gload16(gA,      &sfrag[w][buf][0][0]);
        gload16(gA + 64, &sfrag[w][buf][1][0]);
        gload16(gB,      &sfrag[w][buf][2][0]);
        gload16(gB + 64, &sfrag[w][buf][3][0]);
    };

    issue(0, 0);
    issue(1, 1);

    // ---- main: barrier-free, counted vmcnt, depth-2 DMA pipeline
#pragma unroll 1
    for (int kt = 0; kt < 32; ++kt) {
        const int buf = kt & 1;
        if (kt < 31) { asm volatile("s_waitcnt vmcnt(4)" ::: "memory"); }
        else         { asm volatile("s_waitcnt vmcnt(0)" ::: "memory"); }

        frag_cast e0h, e1h, e0l, e1l;
        e0h.i = sfrag[w][buf][0][lane];
        e1h.i = sfrag[w][buf][1][lane];
        e0l.i = sfrag[w][buf][2][lane];
        e1l.i = sfrag[w][buf][3][lane];
        asm volatile("s_waitcnt lgkmcnt(0)" ::: "memory");   // reads retired before overwrite
        __builtin_amdgcn_sched_barrier(0);
        if (kt < 30) issue(kt + 2, buf);

        const int k = kt * 16 + klane;
        const float enk = en_l[k];
#pragma unroll
        for (int tl = 0; tl < 2; ++tl) {
            // 3 INDEPENDENT 2-MFMA chains (chain depth 2, not 6) -> 3x MFMA ILP
            f32x4 aA = __builtin_amdgcn_mfma_f32_16x16x32_bf16(zh[tl][0], e0h.h, zero, 0, 0, 0);
            f32x4 aB = __builtin_amdgcn_mfma_f32_16x16x32_bf16(zh[tl][0], e0l.h, zero, 0, 0, 0);
            f32x4 aC = __builtin_amdgcn_mfma_f32_16x16x32_bf16(zl[tl][0], e0h.h, zero, 0, 0, 0);
            aA = __builtin_amdgcn_mfma_f32_16x16x32_bf16(zh[tl][1], e1h.h, aA, 0, 0, 0);
            aB = __builtin_amdgcn_mfma_f32_16x16x32_bf16(zh[tl][1], e1l.h, aB, 0, 0, 0);
            aC = __builtin_amdgcn_mfma_f32_16x16x32_bf16(zl[tl][1], e1h.h, aC, 0, 0, 0);
#pragma unroll
            for (int r = 0; r < 4; ++r) {
                float dot = (aA[r] + aB[r]) + aC[r];   // reassociation within W margin
                float d = fmaf(-2.f, dot, enk);        // shifted: zn cancels (r13-18)
                float o1 = m1[tl][r];
                i1[tl][r] = (d < o1) ? k : i1[tl][r];
                m2[tl][r] = fminf(m2[tl][r], fmaxf(o1, d));
                m1[tl][r] = fminf(o1, d);
            }
        }
    }

    // reduce across the 16 code-lanes: xor 1,2,4,8
#pragma unroll
    for (int sh = 1; sh <= 8; sh <<= 1) {
#pragma unroll
        for (int tl = 0; tl < 2; ++tl)
#pragma unroll
            for (int r = 0; r < 4; ++r) {
                float om1 = __shfl_xor(m1[tl][r], sh);
                int oi1 = __shfl_xor(i1[tl][r], sh);
                float om2 = __shfl_xor(m2[tl][r], sh);
                float hi = fmaxf(m1[tl][r], om1);
                m2[tl][r] = fminf(fminf(m2[tl][r], om2), hi);
                i1[tl][r] = (om1 < m1[tl][r]) ? oi1 : i1[tl][r];
                m1[tl][r] = fminf(m1[tl][r], om1);
            }
    }

    if (klane == 0) {
#pragma unroll
        for (int tl = 0; tl < 2; ++tl) {
            int rowbase = n0 + w * 32 + tl * 16 + g * 4;
            i32x4 idx4;
#pragma unroll
            for (int r = 0; r < 4; ++r) idx4[r] = i1[tl][r];
            *(i32x4*)(out + rowbase) = idx4;
#pragma unroll
            for (int r = 0; r < 4; ++r) {
                float zz = zn_l[w * 32 + tl * 16 + g * 4 + r];
                // |split-mfma dist - fp32 dist| bound (~3x margin), validated r5-r18
                float W = fmaf(sqrtf(zz) * emax, 1.0e-4f, zz * 1.0e-6f);
                if (m2[tl][r] - m1[tl][r] <= W) {
                    int p = atomicAdd(&nflag, 1);
                    flag_rows[p] = w * 32 + tl * 16 + g * 4 + r;   // local row
                }
            }
        }
    }
    __syncthreads();

    // ---- in-block exact fp32 refine (k4 semantics); zrow aliases the frag buffer
    float (*zrow_s)[64] = (float(*)[64])&sfrag[0][0][0][0];
    const int nf = nflag;
    for (int i = w; i < nf; i += 4) {
        const int lrow = flag_rows[i];
        zrow_s[w][lane] = zbase[(size_t)lane * 4096 + lrow];
        const float znr = zn_l[lrow];
        float best = 3.4e38f;
        int bi = 0;
#pragma unroll 1
        for (int kk = 0; kk < 8; ++kk) {
            int k = lane * 8 + kk;
            const float* e0 = emb + k * DDIM;
            float acc = 0.f;
#pragma unroll
            for (int d = 0; d < DDIM; ++d) acc = fmaf(e0[d], zrow_s[w][d], acc);
            float dist = fmaf(-2.f, acc, znr + en_l[k]);
            if (dist < best) { best = dist; bi = k; }   // ascending k: first-occurrence
        }
        unsigned long long key =
            ((unsigned long long)__float_as_uint(best) << 32) | (unsigned)bi;
#pragma unroll
        for (int sh = 32; sh; sh >>= 1) {
            unsigned long long o = __shfl_xor(key, sh);
            key = (o < key) ? o : key;
        }
        if (lane == 0) out[n0 + lrow] = (int)(key & 0xFFFFFFFFull);
    }
}

// ---------------- fallback (round-1, known-good) ----------------
__global__ void fb_enorm(const float* __restrict__ emb, float* __restrict__ en) {
    int k = blockIdx.x * blockDim.x + threadIdx.x;
    if (k < KCODES) {
        float s = 0.f;
#pragma unroll
        for (int d = 0; d < DDIM; ++d) { float e = emb[k * DDIM + d]; s = fmaf(e, e, s); }
        en[k] = s;
    }
}
__global__ __launch_bounds__(256) void fb_argmin(const float* __restrict__ z,
                                                 const float* __restrict__ emb,
                                                 const float* __restrict__ en,
                                                 int* __restrict__ out, int nrows) {
    int n = blockIdx.x * blockDim.x + threadIdx.x;
    if (n >= nrows) return;
    int b = n >> 12, hw = n & 4095;
    const float* zp = z + (size_t)b * (DDIM * 4096) + hw;
    float zr[DDIM];
#pragma unroll
    for (int d = 0; d < DDIM; ++d) zr[d] = zp[(size_t)d * 4096];
    float zn = 0.f;
#pragma unroll
    for (int d = 0; d < DDIM; ++d) zn = fmaf(zr[d], zr[d], zn);
    float best = 3.4e38f; int bi = 0;
    for (int k0 = 0; k0 < KCODES; k0 += 8) {
        float acc[8];
#pragma unroll
        for (int kk = 0; kk < 8; ++kk) acc[kk] = 0.f;
        const float* e0 = emb + k0 * DDIM;
#pragma unroll
        for (int d = 0; d < DDIM; ++d) {
            float zd = zr[d];
#pragma unroll
            for (int kk = 0; kk < 8; ++kk) acc[kk] = fmaf(e0[kk * DDIM + d], zd, acc[kk]);
        }
#pragma unroll
        for (int kk = 0; kk < 8; ++kk) {
            float dist = fmaf(-2.f, acc[kk], zn + en[k0 + kk]);
            if (dist < best) { best = dist; bi = k0 + kk; }
        }
    }
    out[n] = bi;
}

extern "C" void kernel_launch(void* const* d_in, const int* in_sizes, int n_in,
                              void* d_out, int out_size, void* d_ws, size_t ws_size,
                              hipStream_t stream) {
    const float* z   = (const float*)d_in[0];   // [32,64,64,64] fp32
    const float* emb = (const float*)d_in[1];   // [512,64] fp32
    int* out = (int*)d_out;                     // 131072 int32

    const size_t SZ_EF   = 32 * 2 * 64 * 16;    // 64 KB each
    const size_t SZ_EN   = KCODES * 4;
    const size_t SZ_EMAX = 128;
    const size_t NEED = 2 * SZ_EF + SZ_EN + SZ_EMAX;   // ~130 KB

    if (ws_size < NEED) {   // safety net: round-1 path
        float* en = (float*)d_ws;
        fb_enorm<<<2, 256, 0, stream>>>(emb, en);
        fb_argmin<<<NROWS / 256, 256, 0, stream>>>(z, emb, en, out, NROWS);
        return;
    }

    char* p = (char*)d_ws;
    i32x4* efA = (i32x4*)p;   p += SZ_EF;
    i32x4* efB = (i32x4*)p;   p += SZ_EF;
    float* en  = (float*)p;   p += SZ_EN;
    float* emaxp = (float*)p;

    k1_prep<<<32, 64, 0, stream>>>(emb, en, emaxp, efA, efB);
    k3_fused<<<NROWS / 128, 256, 0, stream>>>(z, emb, efA, efB, en, emaxp, out);
}

// Round 20
// 77.175 us; speedup vs baseline: 1.1642x; 1.0291x over previous
//
#include <hip/hip_runtime.h>

#define KCODES 512
#define DDIM   64
#define NROWS  131072

typedef short bf16x8 __attribute__((ext_vector_type(8)));
typedef float f32x4  __attribute__((ext_vector_type(4)));
typedef int   i32x4  __attribute__((ext_vector_type(4)));

union frag_cast { i32x4 i; bf16x8 h; };

// packed bf16 RNE convert: [bf16(x1) : bf16(x0)]
__device__ __forceinline__ unsigned cvt_pk_bf16(float x0, float x1) {
    unsigned r;
    asm volatile("v_cvt_pk_bf16_f32 %0, %1, %2" : "=v"(r) : "v"(x0), "v"(x1));
    return r;
}

// split a pair into (hi packed, lo packed)
__device__ __forceinline__ void split_pair(float x0, float x1, unsigned& h, unsigned& l) {
    h = cvt_pk_bf16(x0, x1);
    float hf0 = __uint_as_float(h << 16);
    float hf1 = __uint_as_float(h & 0xffff0000u);
    l = cvt_pk_bf16(x0 - hf0, x1 - hf1);
}

// m2_new = min(m2, max(m1_old, d)) == median(m1_old, m2, d)  (all finite)
__device__ __forceinline__ float med3(float a, float b, float c) {
    float r;
    asm volatile("v_med3_f32 %0, %1, %2, %3" : "=v"(r) : "v"(a), "v"(b), "v"(c));
    return r;
}

// global -> LDS direct DMA, 16B per lane (lds dest = wave-uniform base + lane*16)
__device__ __forceinline__ void gload16(const void* g, void* l) {
    __builtin_amdgcn_global_load_lds(
        (const __attribute__((address_space(1))) void*)g,
        (__attribute__((address_space(3))) void*)l, 16, 0, 0);
}

// ---------------- K1: e_norm + per-block emax + packed split-bf16 B-frags ----------
// 32 blocks x 64 threads; block kt owns codes kt*16..+15.
// efP[kt*256 + slot*64 + lane] (i32x4): slot0=hi_c0,1=hi_c1,2=lo_c0,3=lo_c1;
// lane = krow + 16*gq holds e[kt*16+krow][c*32+gq*8+j], j=0..7.
__global__ __launch_bounds__(64) void k1_prep(const float* __restrict__ emb,
                                              float* __restrict__ en, float* __restrict__ emaxp,
                                              i32x4* __restrict__ efP) {
    const int kt = blockIdx.x, t = threadIdx.x;
    const int krow = t & 15, gq = t >> 4;
    const int k = kt * 16 + krow;

    float er[16];
    float pz = 0.f;
#pragma unroll
    for (int c = 0; c < 2; ++c)
#pragma unroll
        for (int j = 0; j < 8; ++j) {
            float x = emb[k * DDIM + c * 32 + gq * 8 + j];
            er[c * 8 + j] = x;
            pz = fmaf(x, x, pz);
        }

#pragma unroll
    for (int c = 0; c < 2; ++c) {
        i32x4 wh, wl;
#pragma unroll
        for (int i = 0; i < 4; ++i) {
            unsigned h, l;
            split_pair(er[c * 8 + 2 * i], er[c * 8 + 2 * i + 1], h, l);
            wh[i] = (int)h;
            wl[i] = (int)l;
        }
        efP[kt * 256 + c * 64 + krow + 16 * gq]       = wh;
        efP[kt * 256 + (2 + c) * 64 + krow + 16 * gq] = wl;
    }

    pz += __shfl_xor(pz, 16);
    pz += __shfl_xor(pz, 32);
    if (t < 16) en[k] = pz;

    float m = pz;
#pragma unroll
    for (int sh = 1; sh <= 8; sh <<= 1) m = fmaxf(m, __shfl_xor(m, sh));
    if (t == 0) emaxp[kt] = m;   // norm^2 partial max; k3 reduces the 32
}

// ---------------- K3: 4 waves x 2 tiles = 128 rows; wave-private DMA dbuf -----------
// grid 1024 (4 blocks/CU, 16 waves/CU); counted vmcnt, NO barriers in the kt loop.
// CHAMPION configuration: measured 77.5 us total (best of 15 structural variants).
__global__ __launch_bounds__(256, 4) void k3_fused(
    const float* __restrict__ z, const float* __restrict__ emb,
    const i32x4* __restrict__ efP,
    const float* __restrict__ en_g, const float* __restrict__ emaxp,
    int* __restrict__ out) {

    __shared__ i32x4 sfrag[4][2][4][64];   // 32 KB: [wave][buf][slot][lane]
    __shared__ float en_l[KCODES];         // 2 KB
    __shared__ float zn_l[128];
    __shared__ int   flag_rows[128];
    __shared__ int   nflag;
    // ~35.5 KB -> 4 blocks/CU

    const int t = threadIdx.x, blk = blockIdx.x;
    const int n0 = blk * 128;
    const int b = n0 >> 12, hw0 = n0 & 4095;   // 32 blocks per b -> b uniform
    const int w = t >> 6, lane = t & 63;
    const int klane = lane & 15, g = lane >> 4;

    if (t == 0) nflag = 0;

    en_l[t] = en_g[t];
    en_l[t + 256] = en_g[t + 256];

    float em2 = 0.f;
#pragma unroll
    for (int i = 0; i < 32; ++i) em2 = fmaxf(em2, emaxp[i]);
    const float emax = sqrtf(em2) * 1.0001f;

    // ---- z gather + split-bf16 A-frags (cvt_pk) + zn
    const float* zbase = z + (size_t)b * (DDIM * 4096) + hw0;
    bf16x8 zh[2][2], zl[2][2];
#pragma unroll
    for (int tl = 0; tl < 2; ++tl) {
        const int row = w * 32 + tl * 16 + klane;
        float zv[16];
#pragma unroll
        for (int c = 0; c < 2; ++c)
#pragma unroll
            for (int j = 0; j < 8; ++j)
                zv[c * 8 + j] = zbase[(size_t)(c * 32 + g * 8 + j) * 4096 + row];
        float pz = 0.f;
#pragma unroll
        for (int c = 0; c < 2; ++c) {
            frag_cast uh, ul;
#pragma unroll
            for (int i = 0; i < 4; ++i) {
                float x0 = zv[c * 8 + 2 * i], x1 = zv[c * 8 + 2 * i + 1];
                pz = fmaf(x0, x0, pz);
                pz = fmaf(x1, x1, pz);
                unsigned h, l;
                split_pair(x0, x1, h, l);
                uh.i[i] = (int)h;
                ul.i[i] = (int)l;
            }
            zh[tl][c] = uh.h;
            zl[tl][c] = ul.h;
        }
        pz += __shfl_xor(pz, 16);
        pz += __shfl_xor(pz, 32);
        if (g == 0) zn_l[w * 32 + tl * 16 + klane] = pz;
    }
    __syncthreads();   // en_l/zn_l visible; all prologue vmem drained

    float m1[2][4], m2[2][4];
    int i1[2][4];
#pragma unroll
    for (int tl = 0; tl < 2; ++tl)
#pragma unroll
        for (int r = 0; r < 4; ++r) { m1[tl][r] = 3.4e38f; m2[tl][r] = 3.4e38f; i1[tl][r] = 0; }

    f32x4 zero = {0.f, 0.f, 0.f, 0.f};

    // DMA one kt into this wave's buf (4 x 1KB; vmcnt += 4) — no VGPRs consumed
    auto issue = [&](int kt, int buf) {
        const i32x4* src = efP + (size_t)kt * 256 + lane;
        gload16(src,       &sfrag[w][buf][0][0]);
        gload16(src + 64,  &sfrag[w][buf][1][0]);
        gload16(src + 128, &sfrag[w][buf][2][0]);
        gload16(src + 192, &sfrag[w][buf][3][0]);
    };

    issue(0, 0);
    issue(1, 1);

    // ---- main: barrier-free, counted vmcnt, depth-2 DMA pipeline
#pragma unroll 1
    for (int kt = 0; kt < 32; ++kt) {
        const int buf = kt & 1;
        if (kt < 31) { asm volatile("s_waitcnt vmcnt(4)" ::: "memory"); }
        else         { asm volatile("s_waitcnt vmcnt(0)" ::: "memory"); }

        frag_cast e0h, e1h, e0l, e1l;
        e0h.i = sfrag[w][buf][0][lane];
        e1h.i = sfrag[w][buf][1][lane];
        e0l.i = sfrag[w][buf][2][lane];
        e1l.i = sfrag[w][buf][3][lane];
        asm volatile("s_waitcnt lgkmcnt(0)" ::: "memory");   // reads retired before overwrite
        __builtin_amdgcn_sched_barrier(0);
        if (kt < 30) issue(kt + 2, buf);

        const int k = kt * 16 + klane;
        const float enk = en_l[k];
#pragma unroll
        for (int tl = 0; tl < 2; ++tl) {
            f32x4 acc = __builtin_amdgcn_mfma_f32_16x16x32_bf16(zh[tl][0], e0h.h, zero, 0, 0, 0);
            acc = __builtin_amdgcn_mfma_f32_16x16x32_bf16(zh[tl][1], e1h.h, acc, 0, 0, 0);
            acc = __builtin_amdgcn_mfma_f32_16x16x32_bf16(zh[tl][0], e0l.h, acc, 0, 0, 0);
            acc = __builtin_amdgcn_mfma_f32_16x16x32_bf16(zh[tl][1], e1l.h, acc, 0, 0, 0);
            acc = __builtin_amdgcn_mfma_f32_16x16x32_bf16(zl[tl][0], e0h.h, acc, 0, 0, 0);
            acc = __builtin_amdgcn_mfma_f32_16x16x32_bf16(zl[tl][1], e1h.h, acc, 0, 0, 0);
#pragma unroll
            for (int r = 0; r < 4; ++r) {
                float d = fmaf(-2.f, acc[r], enk);   // shifted: zn cancels (validated r13-19)
                float o1 = m1[tl][r];
                i1[tl][r] = (d < o1) ? k : i1[tl][r];
                m2[tl][r] = med3(o1, m2[tl][r], d);  // == min(m2, max(o1,d)), finite
                m1[tl][r] = fminf(o1, d);
            }
        }
    }

    // reduce across the 16 code-lanes: xor 1,2,4,8
#pragma unroll
    for (int sh = 1; sh <= 8; sh <<= 1) {
#pragma unroll
        for (int tl = 0; tl < 2; ++tl)
#pragma unroll
            for (int r = 0; r < 4; ++r) {
                float om1 = __shfl_xor(m1[tl][r], sh);
                int oi1 = __shfl_xor(i1[tl][r], sh);
                float om2 = __shfl_xor(m2[tl][r], sh);
                float hi = fmaxf(m1[tl][r], om1);
                m2[tl][r] = fminf(fminf(m2[tl][r], om2), hi);
                i1[tl][r] = (om1 < m1[tl][r]) ? oi1 : i1[tl][r];
                m1[tl][r] = fminf(m1[tl][r], om1);
            }
    }

    if (klane == 0) {
#pragma unroll
        for (int tl = 0; tl < 2; ++tl) {
            int rowbase = n0 + w * 32 + tl * 16 + g * 4;
            i32x4 idx4;
#pragma unroll
            for (int r = 0; r < 4; ++r) idx4[r] = i1[tl][r];
            *(i32x4*)(out + rowbase) = idx4;
#pragma unroll
            for (int r = 0; r < 4; ++r) {
                float zz = zn_l[w * 32 + tl * 16 + g * 4 + r];
                // |split-mfma dist - fp32 dist| bound (~3x margin), validated r5-r19
                float W = fmaf(sqrtf(zz) * emax, 1.0e-4f, zz * 1.0e-6f);
                if (m2[tl][r] - m1[tl][r] <= W) {
                    int p = atomicAdd(&nflag, 1);
                    flag_rows[p] = w * 32 + tl * 16 + g * 4 + r;   // local row
                }
            }
        }
    }
    __syncthreads();

    // ---- in-block exact fp32 refine (k4 semantics); zrow aliases the frag buffer
    float (*zrow_s)[64] = (float(*)[64])&sfrag[0][0][0][0];
    const int nf = nflag;
    for (int i = w; i < nf; i += 4) {
        const int lrow = flag_rows[i];
        zrow_s[w][lane] = zbase[(size_t)lane * 4096 + lrow];
        const float znr = zn_l[lrow];
        float best = 3.4e38f;
        int bi = 0;
#pragma unroll 1
        for (int kk = 0; kk < 8; ++kk) {
            int k = lane * 8 + kk;
            const float* e0 = emb + k * DDIM;
            float acc = 0.f;
#pragma unroll
            for (int d = 0; d < DDIM; ++d) acc = fmaf(e0[d], zrow_s[w][d], acc);
            float dist = fmaf(-2.f, acc, znr + en_l[k]);
            if (dist < best) { best = dist; bi = k; }   // ascending k: first-occurrence
        }
        unsigned long long key =
            ((unsigned long long)__float_as_uint(best) << 32) | (unsigned)bi;
#pragma unroll
        for (int sh = 32; sh; sh >>= 1) {
            unsigned long long o = __shfl_xor(key, sh);
            key = (o < key) ? o : key;
        }
        if (lane == 0) out[n0 + lrow] = (int)(key & 0xFFFFFFFFull);
    }
}

// ---------------- fallback (round-1, known-good) ----------------
__global__ void fb_enorm(const float* __restrict__ emb, float* __restrict__ en) {
    int k = blockIdx.x * blockDim.x + threadIdx.x;
    if (k < KCODES) {
        float s = 0.f;
#pragma unroll
        for (int d = 0; d < DDIM; ++d) { float e = emb[k * DDIM + d]; s = fmaf(e, e, s); }
        en[k] = s;
    }
}
__global__ __launch_bounds__(256) void fb_argmin(const float* __restrict__ z,
                                                 const float* __restrict__ emb,
                                                 const float* __restrict__ en,
                                                 int* __restrict__ out, int nrows) {
    int n = blockIdx.x * blockDim.x + threadIdx.x;
    if (n >= nrows) return;
    int b = n >> 12, hw = n & 4095;
    const float* zp = z + (size_t)b * (DDIM * 4096) + hw;
    float zr[DDIM];
#pragma unroll
    for (int d = 0; d < DDIM; ++d) zr[d] = zp[(size_t)d * 4096];
    float zn = 0.f;
#pragma unroll
    for (int d = 0; d < DDIM; ++d) zn = fmaf(zr[d], zr[d], zn);
    float best = 3.4e38f; int bi = 0;
    for (int k0 = 0; k0 < KCODES; k0 += 8) {
        float acc[8];
#pragma unroll
        for (int kk = 0; kk < 8; ++kk) acc[kk] = 0.f;
        const float* e0 = emb + k0 * DDIM;
#pragma unroll
        for (int d = 0; d < DDIM; ++d) {
            float zd = zr[d];
#pragma unroll
            for (int kk = 0; kk < 8; ++kk) acc[kk] = fmaf(e0[kk * DDIM + d], zd, acc[kk]);
        }
#pragma unroll
        for (int kk = 0; kk < 8; ++kk) {
            float dist = fmaf(-2.f, acc[kk], zn + en[k0 + kk]);
            if (dist < best) { best = dist; bi = k0 + kk; }
        }
    }
    out[n] = bi;
}

extern "C" void kernel_launch(void* const* d_in, const int* in_sizes, int n_in,
                              void* d_out, int out_size, void* d_ws, size_t ws_size,
                              hipStream_t stream) {
    const float* z   = (const float*)d_in[0];   // [32,64,64,64] fp32
    const float* emb = (const float*)d_in[1];   // [512,64] fp32
    int* out = (int*)d_out;                     // 131072 int32

    const size_t SZ_EF   = 32 * 4 * 64 * 16;    // 128 KB packed frags
    const size_t SZ_EN   = KCODES * 4;
    const size_t SZ_EMAX = 128;
    const size_t NEED = SZ_EF + SZ_EN + SZ_EMAX;   // ~130 KB

    if (ws_size < NEED) {   // safety net: round-1 path
        float* en = (float*)d_ws;
        fb_enorm<<<2, 256, 0, stream>>>(emb, en);
        fb_argmin<<<NROWS / 256, 256, 0, stream>>>(z, emb, en, out, NROWS);
        return;
    }

    char* p = (char*)d_ws;
    i32x4* efP = (i32x4*)p;   p += SZ_EF;
    float* en  = (float*)p;   p += SZ_EN;
    float* emaxp = (float*)p;

    k1_prep<<<32, 64, 0, stream>>>(emb, en, emaxp, efP);
    k3_fused<<<NROWS / 128, 256, 0, stream>>>(z, emb, efP, en, emaxp, out);
}